// Round 1
// baseline (107.111 us; speedup 1.0000x reference)
//
#include <hip/hip_runtime.h>
#include <hip/hip_bf16.h>
#include <cstdint>

// Problem constants (fixed by reference)
#define SEQ   2048
#define CH    1024
#define NHEAD 16
#define KSZ   7
#define NCOL  112      // NHEAD * KSZ
#define PADW  3        // KSZ/2

// Tiling
#define BM       16    // sequence rows per block -> 512 blocks
#define NTHREADS 256   // 4 waves
#define LDK_STR  113   // LDS stride (floats) for predicted kernels
#define NKSTEP   32    // CH / 32 (K-steps of the 16x16x32 MFMA)
#define KSTAGE   4     // K-steps of W staged in LDS at a time (128 k-rows)
#define NSTAGE   (NKSTEP / KSTAGE)            // 8
#define ROWS_PER_STAGE (KSTAGE * 32)          // 128
#define TASKS_PER_STAGE ((ROWS_PER_STAGE/8) * NCOL)   // 16*112 = 1792
#define TASKS_PER_THREAD (TASKS_PER_STAGE / NTHREADS) // 7

typedef __bf16 v8bf __attribute__((ext_vector_type(8)));
typedef float  v4f  __attribute__((ext_vector_type(4)));

// ---------------------------------------------------------------------------
// Single fused kernel, NO workspace, NO prep kernel.
// Phase 1: kernels = x @ W via bf16 MFMA. W (fp32 [1024][112]) is staged
//   through LDS 128 k-rows at a time, pre-packed into the MFMA B-frag
//   layout:  wlds[(((ss*7 + t)*64 + lane)*8 + j)] = W[k = stage*128 + ss*32
//   + (lane>>4)*8 + j][n = t*16 + (lane&15)], so each lane's B-frag is one
//   aligned ds_read_b128 and each staging write is one aligned
//   ds_write_b128 (16-lane-contiguous 256B runs -> bank-uniform).
// Phase 2: dynamic conv with a full 22-row register window (unchanged).
// ---------------------------------------------------------------------------
__global__ __launch_bounds__(NTHREADS, 2)
void dynconv_fused(const float* __restrict__ x,
                   const float* __restrict__ Wp,
                   const float* __restrict__ bp,
                   float* __restrict__ out)
{
    __shared__ float ldsK[BM * LDK_STR];                     // 7,232 B
    __shared__ alignas(16) __bf16 wlds[KSTAGE * 7 * 64 * 8]; // 28,672 B

    const int tid  = threadIdx.x;
    const int bb   = blockIdx.x;          // 0..511
    const int b    = bb >> 7;             // 128 blocks per batch
    const int s0   = (bb & 127) << 4;     // starting sequence row

    const int wave = tid >> 6;
    const int lane = tid & 63;
    const int lq   = lane >> 4;           // quad 0..3
    const int lm   = lane & 15;

    const float* xbase = x + (size_t)b * SEQ * CH;

    // Wave w owns n-tiles {2w, 2w+1}; wave 3 duplicates tile 6 (benign).
    const int tile0 = wave * 2;
    const int tile1 = (wave < 3) ? wave * 2 + 1 : 6;

    v4f acc0 = (v4f){0.f, 0.f, 0.f, 0.f};
    v4f acc1 = (v4f){0.f, 0.f, 0.f, 0.f};

    // A-frag base: lane (lq,lm) reads x[s0+lm][k = s*32 + lq*8 .. +7]
    const float* arow = xbase + (size_t)(s0 + lm) * CH + lq * 8;

    for (int st = 0; st < NSTAGE; ++st) {
        if (st) __syncthreads();   // prev stage's frags fully consumed

        // ---- stage 128 rows of W into LDS as packed B-frags ----
        // Task = (8-k-row group g8, column n): 8 strided L2-hot scalar
        // loads -> one packed v8bf -> one ds_write_b128.
        #pragma unroll
        for (int t = 0; t < TASKS_PER_THREAD; ++t) {
            const int task = t * NTHREADS + tid;     // 0..1791
            const int g8   = task / NCOL;            // 0..15
            const int n    = task - g8 * NCOL;       // 0..111
            const int k0   = st * ROWS_PER_STAGE + g8 * 8;
            const int sloc = g8 >> 2;                // K-step within stage
            const int lqw  = g8 & 3;                 // quad within K-step
            const float* wp = Wp + (size_t)k0 * NCOL + n;
            v8bf bv;
            #pragma unroll
            for (int j = 0; j < 8; ++j)
                bv[j] = (__bf16)wp[(size_t)j * NCOL];
            const int gran = (sloc * 7 + (n >> 4)) * 64 + lqw * 16 + (n & 15);
            *(v8bf*)&wlds[(size_t)gran * 8] = bv;
        }
        __syncthreads();

        // ---- 4 K-steps of MFMA from this stage ----
        #pragma unroll
        for (int ss = 0; ss < KSTAGE; ++ss) {
            const int s = st * KSTAGE + ss;
            const float* p = arow + s * 32;
            const v4f v0 = *(const v4f*)p;
            const v4f v1 = *(const v4f*)(p + 4);
            v8bf af;
            af[0] = (__bf16)v0.x; af[1] = (__bf16)v0.y;
            af[2] = (__bf16)v0.z; af[3] = (__bf16)v0.w;
            af[4] = (__bf16)v1.x; af[5] = (__bf16)v1.y;
            af[6] = (__bf16)v1.z; af[7] = (__bf16)v1.w;

            const v8bf bf0 = *(const v8bf*)&wlds[(size_t)((ss*7 + tile0)*64 + lane)*8];
            const v8bf bf1 = *(const v8bf*)&wlds[(size_t)((ss*7 + tile1)*64 + lane)*8];
            acc0 = __builtin_amdgcn_mfma_f32_16x16x32_bf16(af, bf0, acc0, 0, 0, 0);
            acc1 = __builtin_amdgcn_mfma_f32_16x16x32_bf16(af, bf1, acc1, 0, 0, 0);
        }
    }

    // Epilogue: bias + scatter to ldsK.
    // C/D layout: col = lane&15, row = (lane>>4)*4 + reg  [m89/m91 verified]
    {
        const int ct0 = tile0 * 16 + lm;
        const float bias0 = bp[ct0];
        #pragma unroll
        for (int r = 0; r < 4; ++r)
            ldsK[(lq * 4 + r) * LDK_STR + ct0] = acc0[r] + bias0;
        if (wave < 3) {
            const int ct1 = tile1 * 16 + lm;
            const float bias1 = bp[ct1];
            #pragma unroll
            for (int r = 0; r < 4; ++r)
                ldsK[(lq * 4 + r) * LDK_STR + ct1] = acc1[r] + bias1;
        }
    }

    // ---- Phase 2: dynamic conv ----
    // Thread owns channels [4*tid, 4*tid+3]; head h = tid>>4.
    // Preload the full 22-row window BEFORE the barrier so the barrier wait
    // overlaps the load latency.
    const int h  = tid >> 4;
    const int c4 = tid << 2;

    v4f win[BM + 6];
    #pragma unroll
    for (int i = 0; i < BM + 6; ++i) {
        const int sg = s0 - PADW + i;
        win[i] = (sg >= 0 && sg < SEQ)
                     ? *(const v4f*)(xbase + (size_t)sg * CH + c4)
                     : (v4f){0.f, 0.f, 0.f, 0.f};
    }

    __syncthreads();

    float* orow = out + ((size_t)b * SEQ + s0) * CH + c4;
    #pragma unroll
    for (int r = 0; r < BM; ++r) {
        const float* kp = &ldsK[r * LDK_STR + h * KSZ];
        v4f a = (v4f){0.f, 0.f, 0.f, 0.f};
        #pragma unroll
        for (int i = 0; i < KSZ; ++i) {
            a += kp[i] * win[r + i];
        }
        *(v4f*)(orow + (size_t)r * CH) = a;
    }
}

extern "C" void kernel_launch(void* const* d_in, const int* in_sizes, int n_in,
                              void* d_out, int out_size, void* d_ws, size_t ws_size,
                              hipStream_t stream) {
    const float* x  = (const float*)d_in[0];
    const float* Wp = (const float*)d_in[1];
    const float* bp = (const float*)d_in[2];
    float* out = (float*)d_out;
    (void)d_ws; (void)ws_size;   // workspace deliberately unused

    dynconv_fused<<<dim3(512), dim3(NTHREADS), 0, stream>>>(x, Wp, bp, out);
}

// Round 2
// 104.569 us; speedup vs baseline: 1.0243x; 1.0243x over previous
//
#include <hip/hip_runtime.h>
#include <hip/hip_bf16.h>
#include <cstdint>

// Problem constants (fixed by reference)
#define SEQ   2048
#define CH    1024
#define NHEAD 16
#define KSZ   7
#define NCOL  112      // NHEAD * KSZ
#define PADW  3        // KSZ/2

// Tiling
#define BM       16    // sequence rows per block -> 512 blocks
#define NTHREADS 256   // 4 waves
#define LDK_STR  113   // LDS stride (floats) for predicted kernels
#define NKSTEP   32    // CH / 32 (K-steps of the 16x16x32 MFMA)
#define WS_FRAG_BYTES (NKSTEP * 7 * 64 * 16)   // 229,376 B of pre-packed B-frags

typedef __bf16 v8bf __attribute__((ext_vector_type(8)));
typedef float  v4f  __attribute__((ext_vector_type(4)));

// ---------------------------------------------------------------------------
// Prologue: convert W_pred (fp32 [1024][112]) to bf16 packed in MFMA B-frag
// order: ws[(((s*7 + t)*64 + lane)*8 + j)] = W[k = s*32 + (lane>>4)*8 + j]
//                                             [n = t*16 + (lane&15)]
// so the GEMM loads each B-frag as one coalesced dwordx4 per lane.
// Cost: one tiny dispatch (~114K elements), W stays L2-resident for the
// main kernel. In-kernel alternative (LDS staging, Round 1) measured +2.4us.
// ---------------------------------------------------------------------------
__global__ __launch_bounds__(256)
void prep_w(const float* __restrict__ Wp, __bf16* __restrict__ wsB) {
    const int g  = blockIdx.x * 256 + threadIdx.x;   // 0..114687
    const int j  = g & 7;
    const int l  = (g >> 3) & 63;
    const int st = g >> 9;            // s*7 + t, 0..223
    const int s  = st / 7;
    const int t  = st - s * 7;
    const int k  = s * 32 + (l >> 4) * 8 + j;
    const int n  = t * 16 + (l & 15);
    wsB[g] = (__bf16)Wp[k * NCOL + n];
}

// ---------------------------------------------------------------------------
// Fused kernel: per block, 16 seq rows of one batch.
// Phase 1: kernels = x @ W (bf16 MFMA, barrier-free K-loop, B-frags from ws).
// Phase 2: dynamic conv with a full 22-row register window.
// Out is stored non-temporally: write-once data must not evict the W-frag
// table (229KB, shared by all 512 blocks) or x halo rows from L2.
// ---------------------------------------------------------------------------
template <bool PRE>
__global__ __launch_bounds__(NTHREADS, 2)
void dynconv_fused(const float* __restrict__ x,
                   const float* __restrict__ Wp,
                   const float* __restrict__ bp,
                   const __bf16* __restrict__ wsB,
                   float* __restrict__ out)
{
    __shared__ float ldsK[BM * LDK_STR];   // 7,232 B

    const int tid  = threadIdx.x;
    const int bb   = blockIdx.x;          // 0..511
    const int b    = bb >> 7;             // 128 blocks per batch
    const int s0   = (bb & 127) << 4;     // starting sequence row

    const int wave = tid >> 6;
    const int lane = tid & 63;
    const int lq   = lane >> 4;           // quad 0..3
    const int lm   = lane & 15;

    const float* xbase = x + (size_t)b * SEQ * CH;

    // ---- Phase 1: GEMM ----
    // Wave w owns n-tiles {2w, 2w+1}; wave 3 duplicates tile 6 (benign).
    const int tile0 = wave * 2;
    const int tile1 = (wave < 3) ? wave * 2 + 1 : 6;

    v4f acc0 = (v4f){0.f, 0.f, 0.f, 0.f};
    v4f acc1 = (v4f){0.f, 0.f, 0.f, 0.f};

    // A-frag base: lane (lq,lm) reads x[s0+lm][k = s*32 + lq*8 .. +7]
    const float* arow = xbase + (size_t)(s0 + lm) * CH + lq * 8;

    #pragma unroll 8
    for (int s = 0; s < NKSTEP; ++s) {
        const float* p = arow + s * 32;
        const v4f v0 = *(const v4f*)p;
        const v4f v1 = *(const v4f*)(p + 4);
        v8bf af;
        af[0] = (__bf16)v0.x; af[1] = (__bf16)v0.y;
        af[2] = (__bf16)v0.z; af[3] = (__bf16)v0.w;
        af[4] = (__bf16)v1.x; af[5] = (__bf16)v1.y;
        af[6] = (__bf16)v1.z; af[7] = (__bf16)v1.w;

        v8bf bf0, bf1;
        if (PRE) {
            bf0 = *(const v8bf*)&wsB[(size_t)((s * 7 + tile0) * 64 + lane) * 8];
            bf1 = *(const v8bf*)&wsB[(size_t)((s * 7 + tile1) * 64 + lane) * 8];
        } else {
            #pragma unroll
            for (int j = 0; j < 8; ++j) {
                const int k = s * 32 + lq * 8 + j;
                bf0[j] = (__bf16)Wp[k * NCOL + tile0 * 16 + lm];
                bf1[j] = (__bf16)Wp[k * NCOL + tile1 * 16 + lm];
            }
        }
        acc0 = __builtin_amdgcn_mfma_f32_16x16x32_bf16(af, bf0, acc0, 0, 0, 0);
        acc1 = __builtin_amdgcn_mfma_f32_16x16x32_bf16(af, bf1, acc1, 0, 0, 0);
    }

    // Epilogue: bias + scatter to ldsK.
    // C/D layout: col = lane&15, row = (lane>>4)*4 + reg  [m89/m91 verified]
    {
        const int ct0 = tile0 * 16 + lm;
        const float bias0 = bp[ct0];
        #pragma unroll
        for (int r = 0; r < 4; ++r)
            ldsK[(lq * 4 + r) * LDK_STR + ct0] = acc0[r] + bias0;
        if (wave < 3) {
            const int ct1 = tile1 * 16 + lm;
            const float bias1 = bp[ct1];
            #pragma unroll
            for (int r = 0; r < 4; ++r)
                ldsK[(lq * 4 + r) * LDK_STR + ct1] = acc1[r] + bias1;
        }
    }

    // ---- Phase 2: dynamic conv ----
    // Thread owns channels [4*tid, 4*tid+3]; head h = tid>>4.
    // Preload the full 22-row window into registers BEFORE the barrier so the
    // barrier wait overlaps the load latency.
    const int h  = tid >> 4;
    const int c4 = tid << 2;

    v4f win[BM + 6];
    #pragma unroll
    for (int i = 0; i < BM + 6; ++i) {
        const int sg = s0 - PADW + i;
        win[i] = (sg >= 0 && sg < SEQ)
                     ? *(const v4f*)(xbase + (size_t)sg * CH + c4)
                     : (v4f){0.f, 0.f, 0.f, 0.f};
    }

    __syncthreads();

    float* orow = out + ((size_t)b * SEQ + s0) * CH + c4;
    #pragma unroll
    for (int r = 0; r < BM; ++r) {
        const float* kp = &ldsK[r * LDK_STR + h * KSZ];
        v4f a = (v4f){0.f, 0.f, 0.f, 0.f};
        #pragma unroll
        for (int i = 0; i < KSZ; ++i) {
            a += kp[i] * win[r + i];
        }
        // Non-temporal: out is write-once, keep it out of L2.
        __builtin_nontemporal_store(a, (v4f*)(orow + (size_t)r * CH));
    }
}

extern "C" void kernel_launch(void* const* d_in, const int* in_sizes, int n_in,
                              void* d_out, int out_size, void* d_ws, size_t ws_size,
                              hipStream_t stream) {
    const float* x  = (const float*)d_in[0];
    const float* Wp = (const float*)d_in[1];
    const float* bp = (const float*)d_in[2];
    float* out = (float*)d_out;

    if (ws_size >= (size_t)WS_FRAG_BYTES) {
        __bf16* wsB = (__bf16*)d_ws;
        prep_w<<<dim3(448), dim3(256), 0, stream>>>(Wp, wsB);
        dynconv_fused<true><<<dim3(512), dim3(NTHREADS), 0, stream>>>(x, Wp, bp, wsB, out);
    } else {
        dynconv_fused<false><<<dim3(512), dim3(NTHREADS), 0, stream>>>(x, Wp, bp, nullptr, out);
    }
}

// Round 4
// 103.303 us; speedup vs baseline: 1.0369x; 1.0123x over previous
//
#include <hip/hip_runtime.h>
#include <hip/hip_bf16.h>
#include <cstdint>

// Problem constants (fixed by reference)
#define SEQ   2048
#define CH    1024
#define NHEAD 16
#define KSZ   7
#define NCOL  112      // NHEAD * KSZ
#define PADW  3        // KSZ/2

// Tiling
#define BM       16    // sequence rows per block -> 512 blocks
#define NTHREADS 256   // 4 waves
#define LDK_STR  113   // LDS stride (floats) for predicted kernels
#define NKSTEP   32    // CH / 32 (K-steps of the 16x16x32 MFMA)
#define WS_FRAG_BYTES (NKSTEP * 7 * 64 * 16)   // 229,376 B of pre-packed B-frags

typedef __bf16 v8bf __attribute__((ext_vector_type(8)));
typedef float  v4f  __attribute__((ext_vector_type(4)));

// ---------------------------------------------------------------------------
// Prologue: convert W_pred (fp32 [1024][112]) to bf16 packed in MFMA B-frag
// order: ws[(((s*7 + t)*64 + lane)*8 + j)] = W[k = s*32 + (lane>>4)*8 + j]
//                                             [n = t*16 + (lane&15)]
// so the GEMM loads each B-frag as one coalesced dwordx4 per lane.
// Cost: one tiny dispatch (~114K elements), W stays L2-resident for the
// main kernel. In-kernel alternative (LDS staging, Round 1) measured +2.4us.
// An LDS-staged A-tile variant (Round 3) failed correctness; reverted.
// ---------------------------------------------------------------------------
__global__ __launch_bounds__(256)
void prep_w(const float* __restrict__ Wp, __bf16* __restrict__ wsB) {
    const int g  = blockIdx.x * 256 + threadIdx.x;   // 0..114687
    const int j  = g & 7;
    const int l  = (g >> 3) & 63;
    const int st = g >> 9;            // s*7 + t, 0..223
    const int s  = st / 7;
    const int t  = st - s * 7;
    const int k  = s * 32 + (l >> 4) * 8 + j;
    const int n  = t * 16 + (l & 15);
    wsB[g] = (__bf16)Wp[k * NCOL + n];
}

// ---------------------------------------------------------------------------
// Fused kernel: per block, 16 seq rows of one batch.
// Phase 1: kernels = x @ W (bf16 MFMA, barrier-free K-loop, B-frags from ws).
// Phase 2: dynamic conv with a full 22-row register window.
// Out is stored non-temporally: write-once data must not evict the W-frag
// table (229KB, shared by all 512 blocks) or x halo rows from L2.
// ---------------------------------------------------------------------------
template <bool PRE>
__global__ __launch_bounds__(NTHREADS, 2)
void dynconv_fused(const float* __restrict__ x,
                   const float* __restrict__ Wp,
                   const float* __restrict__ bp,
                   const __bf16* __restrict__ wsB,
                   float* __restrict__ out)
{
    __shared__ float ldsK[BM * LDK_STR];   // 7,232 B

    const int tid  = threadIdx.x;
    const int bb   = blockIdx.x;          // 0..511
    const int b    = bb >> 7;             // 128 blocks per batch
    const int s0   = (bb & 127) << 4;     // starting sequence row

    const int wave = tid >> 6;
    const int lane = tid & 63;
    const int lq   = lane >> 4;           // quad 0..3
    const int lm   = lane & 15;

    const float* xbase = x + (size_t)b * SEQ * CH;

    // ---- Phase 1: GEMM ----
    // Wave w owns n-tiles {2w, 2w+1}; wave 3 duplicates tile 6 (benign).
    const int tile0 = wave * 2;
    const int tile1 = (wave < 3) ? wave * 2 + 1 : 6;

    v4f acc0 = (v4f){0.f, 0.f, 0.f, 0.f};
    v4f acc1 = (v4f){0.f, 0.f, 0.f, 0.f};

    // A-frag base: lane (lq,lm) reads x[s0+lm][k = s*32 + lq*8 .. +7]
    const float* arow = xbase + (size_t)(s0 + lm) * CH + lq * 8;

    #pragma unroll 8
    for (int s = 0; s < NKSTEP; ++s) {
        const float* p = arow + s * 32;
        const v4f v0 = *(const v4f*)p;
        const v4f v1 = *(const v4f*)(p + 4);
        v8bf af;
        af[0] = (__bf16)v0.x; af[1] = (__bf16)v0.y;
        af[2] = (__bf16)v0.z; af[3] = (__bf16)v0.w;
        af[4] = (__bf16)v1.x; af[5] = (__bf16)v1.y;
        af[6] = (__bf16)v1.z; af[7] = (__bf16)v1.w;

        v8bf bf0, bf1;
        if (PRE) {
            bf0 = *(const v8bf*)&wsB[(size_t)((s * 7 + tile0) * 64 + lane) * 8];
            bf1 = *(const v8bf*)&wsB[(size_t)((s * 7 + tile1) * 64 + lane) * 8];
        } else {
            #pragma unroll
            for (int j = 0; j < 8; ++j) {
                const int k = s * 32 + lq * 8 + j;
                bf0[j] = (__bf16)Wp[k * NCOL + tile0 * 16 + lm];
                bf1[j] = (__bf16)Wp[k * NCOL + tile1 * 16 + lm];
            }
        }
        acc0 = __builtin_amdgcn_mfma_f32_16x16x32_bf16(af, bf0, acc0, 0, 0, 0);
        acc1 = __builtin_amdgcn_mfma_f32_16x16x32_bf16(af, bf1, acc1, 0, 0, 0);
    }

    // Epilogue: bias + scatter to ldsK.
    // C/D layout: col = lane&15, row = (lane>>4)*4 + reg  [m89/m91 verified]
    {
        const int ct0 = tile0 * 16 + lm;
        const float bias0 = bp[ct0];
        #pragma unroll
        for (int r = 0; r < 4; ++r)
            ldsK[(lq * 4 + r) * LDK_STR + ct0] = acc0[r] + bias0;
        if (wave < 3) {
            const int ct1 = tile1 * 16 + lm;
            const float bias1 = bp[ct1];
            #pragma unroll
            for (int r = 0; r < 4; ++r)
                ldsK[(lq * 4 + r) * LDK_STR + ct1] = acc1[r] + bias1;
        }
    }

    // ---- Phase 2: dynamic conv ----
    // Thread owns channels [4*tid, 4*tid+3]; head h = tid>>4.
    // Preload the full 22-row window into registers BEFORE the barrier so the
    // barrier wait overlaps the load latency.
    const int h  = tid >> 4;
    const int c4 = tid << 2;

    v4f win[BM + 6];
    #pragma unroll
    for (int i = 0; i < BM + 6; ++i) {
        const int sg = s0 - PADW + i;
        win[i] = (sg >= 0 && sg < SEQ)
                     ? *(const v4f*)(xbase + (size_t)sg * CH + c4)
                     : (v4f){0.f, 0.f, 0.f, 0.f};
    }

    __syncthreads();

    float* orow = out + ((size_t)b * SEQ + s0) * CH + c4;
    #pragma unroll
    for (int r = 0; r < BM; ++r) {
        const float* kp = &ldsK[r * LDK_STR + h * KSZ];
        v4f a = (v4f){0.f, 0.f, 0.f, 0.f};
        #pragma unroll
        for (int i = 0; i < KSZ; ++i) {
            a += kp[i] * win[r + i];
        }
        // Non-temporal: out is write-once, keep it out of L2.
        __builtin_nontemporal_store(a, (v4f*)(orow + (size_t)r * CH));
    }
}

extern "C" void kernel_launch(void* const* d_in, const int* in_sizes, int n_in,
                              void* d_out, int out_size, void* d_ws, size_t ws_size,
                              hipStream_t stream) {
    const float* x  = (const float*)d_in[0];
    const float* Wp = (const float*)d_in[1];
    const float* bp = (const float*)d_in[2];
    float* out = (float*)d_out;

    if (ws_size >= (size_t)WS_FRAG_BYTES) {
        __bf16* wsB = (__bf16*)d_ws;
        prep_w<<<dim3(448), dim3(256), 0, stream>>>(Wp, wsB);
        dynconv_fused<true><<<dim3(512), dim3(NTHREADS), 0, stream>>>(x, Wp, bp, wsB, out);
    } else {
        dynconv_fused<false><<<dim3(512), dim3(NTHREADS), 0, stream>>>(x, Wp, bp, nullptr, out);
    }
}